// Round 3
// baseline (173.015 us; speedup 1.0000x reference)
//
#include <hip/hip_runtime.h>
#include <hip/hip_cooperative_groups.h>

namespace cg = cooperative_groups;

// ---- problem constants ----
#define NCAM      6
#define NB        4
#define NROWS     24          // NB*NCAM
#define NQ        65536       // 256*256
#define MAXLEN_   65536

// flat f32 offsets into d_out (return order)
#define OFF_QGRID   0
#define OFF_RESTORE 3145728    // 24*65536*2
#define OFF_REFPTS  6291456    // + 4*6*256*256*2
#define OFF_COUNTS  18874368   // + 24*65536*4*2

// z values of the 4 pillar points, f32-linspace path
__device__ __forceinline__ float zval(int d) {
    const float z[4] = { -4.5f, -2.16666674613952637f,
                          0.166666507720947266f, 2.5f };
    return z[d];
}

__device__ __forceinline__ float clip21(float x) {
    return fminf(fmaxf(x, -2.1f), 2.1f);
}

// project one 3D point through rows 0..2 of the 4x4 matrix; returns vis
// (bit-identical to the round-1/2 passing versions)
__device__ __forceinline__ bool proj_point(const float m[12], float x, float y, float z,
                                           float& u, float& v) {
    float c0 = ((m[0]*x + m[1]*y) + m[2]*z) + m[3];
    float c1 = ((m[4]*x + m[5]*y) + m[6]*z) + m[7];
    float c2 = ((m[8]*x + m[9]*y) + m[10]*z) + m[11];
    float zcl = fmaxf(c2, 1e-5f);
    u = (c0 / zcl) / 928.0f;   // IMW
    v = (c1 / zcl) / 512.0f;   // IMH
    return (c2 > 1e-5f) & (v > 0.0f) & (v < 1.0f) & (u < 1.0f) & (u > 0.0f);
}

__device__ __forceinline__ void load_mat(const float* __restrict__ ego2img, int row, float m[12]) {
    const float* M = ego2img + row * 16;
    #pragma unroll
    for (int i = 0; i < 12; ++i) m[i] = M[i];
}

__device__ __forceinline__ void bev_xy(int qx, int qy, float& x, float& y) {
    x = ((float)qx + 0.5f) * (1.0f/256.0f) * 102.4f - 51.2f;
    y = ((float)qy + 0.5f) * (1.0f/256.0f) * 102.4f - 51.2f;
}

// ---------- single cooperative kernel ----------
// grid (256, NB), 256 threads. Block = one BEV row (qy = blockIdx.x) of one
// batch, all 6 cameras. Phase A: per-block per-camera visible counts.
// grid.sync(). Phase B: per-camera prefix over the 256 row-counts, packed
// scatter, tail fill, restore grid, pillar counts. All from LDS ranks.
__global__ void __launch_bounds__(256, 4)
k_all(const float* __restrict__ ego2img, int* __restrict__ counts,
      float* __restrict__ out)
{
    int chunk = blockIdx.x, b = blockIdx.y;
    int t = threadIdx.x;
    int lane = t & 63, wid = t >> 6;
    int qx = t, qy = chunk;
    int q = chunk * 256 + t;
    float x, y; bev_xy(qx, qy, x, y);

    __shared__ int wcnt[NCAM][4];
    __shared__ int sBase[NCAM], sTotal[NCAM];
    __shared__ int waveIncl[NCAM][4];
    __shared__ int ranks[NCAM][256];

    // ---- Phase A: per-camera visibility counts for this block's 256 q's ----
    for (int c = 0; c < NCAM; ++c) {
        float m[12]; load_mat(ego2img, b * NCAM + c, m);
        bool vis = false;
        #pragma unroll
        for (int d = 0; d < 4; ++d) {
            float u, v;
            vis |= proj_point(m, x, y, zval(d), u, v);
        }
        unsigned long long bal = __ballot(vis);
        if (lane == 0) wcnt[c][wid] = __popcll(bal);
    }
    __syncthreads();
    if (t < NCAM)
        counts[(b * NCAM + t) * 256 + chunk] =
            wcnt[t][0] + wcnt[t][1] + wcnt[t][2] + wcnt[t][3];

    cg::this_grid().sync();

    // ---- Phase B0: per-camera exclusive prefix over the 256 row counts ----
    for (int c = wid; c < NCAM; c += 4) {
        const int* p = counts + (b * NCAM + c) * 256;
        int4 v4 = ((const int4*)p)[lane];            // 4 consecutive counts
        int s = v4.x + v4.y + v4.z + v4.w;
        int incl = s;
        #pragma unroll
        for (int off = 1; off < 64; off <<= 1) {
            int n = __shfl_up(incl, off, 64);
            if (lane >= off) incl += n;
        }
        if (lane == (chunk >> 2)) {
            int base = incl - s;
            int k = chunk & 3;
            if (k > 0) base += v4.x;
            if (k > 1) base += v4.y;
            if (k > 2) base += v4.z;
            sBase[c] = base;
        }
        if (lane == 63) sTotal[c] = incl;
    }

    // ---- Phase B1: per camera — project, scan, packed scatter, tail fill ----
    for (int c = 0; c < NCAM; ++c) {
        float m[12]; load_mat(ego2img, b * NCAM + c, m);
        float uv[8];
        bool vis = false;
        #pragma unroll
        for (int d = 0; d < 4; ++d) {
            float u, v;
            bool vi = proj_point(m, x, y, zval(d), u, v);
            uv[2*d]   = clip21(u);
            uv[2*d+1] = clip21(v);
            vis |= vi;
        }
        int cnt = vis ? 1 : 0;
        int incl = cnt;
        #pragma unroll
        for (int off = 1; off < 64; off <<= 1) {
            int n = __shfl_up(incl, off, 64);
            if (lane >= off) incl += n;
        }
        if (lane == 63) waveIncl[c][wid] = incl;
        __syncthreads();
        int base = sBase[c];
        #pragma unroll
        for (int w = 0; w < 3; ++w) if (w < wid) base += waveIncl[c][w];
        int r = base + incl - cnt;   // packed rank of this q if visible

        float2* qgrid = (float2*)(out + OFF_QGRID)  + (size_t)(b * NCAM + c) * MAXLEN_;
        float4* refp  = (float4*)(out + OFF_REFPTS) + (size_t)(b * NCAM + c) * MAXLEN_ * 2;

        if (vis) {
            float2 g;
            g.x = ((float)qx / 255.0f) * 2.0f - 1.0f;
            g.y = ((float)qy / 255.0f) * 2.0f - 1.0f;
            qgrid[r] = g;
            refp[2*r]   = make_float4(uv[0], uv[1], uv[2], uv[3]);
            refp[2*r+1] = make_float4(uv[4], uv[5], uv[6], uv[7]);
            ranks[c][t] = r;
        } else {
            ranks[c][t] = -1;
        }
        // tail fill: slots >= row total get defaults (covers all slots once)
        if (q >= sTotal[c]) {
            qgrid[q] = make_float2(-1.5f, -1.5f);
            float4 z4 = make_float4(0.f, 0.f, 0.f, 0.f);
            refp[2*q]   = z4;
            refp[2*q+1] = z4;
        }
    }
    __syncthreads();

    // ---- Phase B2: restore grid + pillar counts from LDS ranks ----
    float2* rest = (float2*)(out + OFF_RESTORE) + (size_t)b * NCAM * NQ;
    int over = 0;
    #pragma unroll
    for (int c = 0; c < NCAM; ++c) {
        int r = ranks[c][t];
        if (r >= 0) {
            float gx = ((float)(r & 255) / 255.0f) * 2.0f - 1.0f;
            float gy = ((float)(c * 256 + (r >> 8)) / 1535.0f) * 2.0f - 1.0f;
            rest[(over * 256 + qy) * 256 + qx] = make_float2(gx, gy);
            ++over;
        }
    }
    for (int o = over; o < NCAM; ++o)
        rest[(o * 256 + qy) * 256 + qx] = make_float2(-1.5f, -1.5f);
    out[OFF_COUNTS + b * NQ + q] = 1.0f / fmaxf((float)over, 1.0f);
}

extern "C" void kernel_launch(void* const* d_in, const int* in_sizes, int n_in,
                              void* d_out, int out_size, void* d_ws, size_t ws_size,
                              hipStream_t stream)
{
    const float* ego2img = (const float*)d_in[0];
    float* out = (float*)d_out;
    int* counts = (int*)d_ws;   // 24*256 ints = 24.6 KB

    void* args[] = { (void*)&ego2img, (void*)&counts, (void*)&out };
    hipLaunchCooperativeKernel((const void*)k_all, dim3(256, NB), dim3(256, 1, 1),
                               args, 0, stream);
}

// Round 4
// 99.611 us; speedup vs baseline: 1.7369x; 1.7369x over previous
//
#include <hip/hip_runtime.h>

// ---- problem constants ----
#define NCAM      6
#define NB        4
#define NROWS     24          // NB*NCAM
#define NQ        65536       // 256*256
#define MAXLEN_   65536

// flat f32 offsets into d_out (return order)
#define OFF_QGRID   0
#define OFF_RESTORE 3145728    // 24*65536*2
#define OFF_REFPTS  6291456    // + 4*6*256*256*2
#define OFF_COUNTS  18874368   // + 24*65536*4*2

// z values of the 4 pillar points, f32-linspace path
__device__ __forceinline__ float zval(int d) {
    const float z[4] = { -4.5f, -2.16666674613952637f,
                          0.166666507720947266f, 2.5f };
    return z[d];
}

__device__ __forceinline__ float clip21(float x) {
    return fminf(fmaxf(x, -2.1f), 2.1f);
}

// project one 3D point through rows 0..2 of the 4x4 matrix; returns vis
// (bit-identical to the round-1/2 passing versions)
__device__ __forceinline__ bool proj_point(const float m[12], float x, float y, float z,
                                           float& u, float& v) {
    float c0 = ((m[0]*x + m[1]*y) + m[2]*z) + m[3];
    float c1 = ((m[4]*x + m[5]*y) + m[6]*z) + m[7];
    float c2 = ((m[8]*x + m[9]*y) + m[10]*z) + m[11];
    float zcl = fmaxf(c2, 1e-5f);
    u = (c0 / zcl) / 928.0f;   // IMW
    v = (c1 / zcl) / 512.0f;   // IMH
    return (c2 > 1e-5f) & (v > 0.0f) & (v < 1.0f) & (u < 1.0f) & (u > 0.0f);
}

__device__ __forceinline__ void load_mat(const float* __restrict__ ego2img, int row, float m[12]) {
    const float* M = ego2img + row * 16;
    #pragma unroll
    for (int i = 0; i < 12; ++i) m[i] = M[i];
}

__device__ __forceinline__ void bev_xy(int qx, int qy, float& x, float& y) {
    x = ((float)qx + 0.5f) * (1.0f/256.0f) * 102.4f - 51.2f;
    y = ((float)qy + 0.5f) * (1.0f/256.0f) * 102.4f - 51.2f;
}

// ---------- kernel 1: per-256q-subchunk visible-pillar counts ----------
// grid (64, 24), 256 threads. Each wave owns 256 consecutive q -> one count.
__global__ void __launch_bounds__(256)
k_count(const float* __restrict__ ego2img, int* __restrict__ chunkCounts)
{
    int chunk = blockIdx.x, row = blockIdx.y;
    float m[12]; load_mat(ego2img, row, m);
    int t = threadIdx.x;
    int q0 = chunk * 1024 + t * 4;
    int cnt = 0;
    #pragma unroll
    for (int i = 0; i < 4; ++i) {
        int q = q0 + i;
        float x, y; bev_xy(q & 255, q >> 8, x, y);
        bool va = false;
        #pragma unroll
        for (int d = 0; d < 4; ++d) {
            float u, v;
            va |= proj_point(m, x, y, zval(d), u, v);
        }
        cnt += va ? 1 : 0;
    }
    #pragma unroll
    for (int off = 32; off > 0; off >>= 1) cnt += __shfl_down(cnt, off, 64);
    if ((t & 63) == 0)
        chunkCounts[row * 256 + chunk * 4 + (t >> 6)] = cnt;
}

// ---------- kernel 2: fused pack + restore + counts ----------
// grid (256, NB), 256 threads. Block = one BEV row (qy = blockIdx.x) of one
// batch, all 6 cameras. Ranks stay in registers; restore row staged in LDS
// so global restore writes are 6 fully-coalesced 2KB runs (no partial lines).
__global__ void __launch_bounds__(256)
k_fused(const float* __restrict__ ego2img, const int* __restrict__ chunkCounts,
        float* __restrict__ out)
{
    int chunk = blockIdx.x, b = blockIdx.y;
    int t = threadIdx.x;
    int lane = t & 63, wid = t >> 6;

    __shared__ int sBase[NCAM], sTotal[NCAM];
    __shared__ int waveIncl[NCAM][4];
    __shared__ float2 srow[NCAM][256];     // staged restore row

    // phase 0: per-camera exclusive prefix over the row's 256 subchunk counts
    for (int c = wid; c < NCAM; c += 4) {
        const int* p = chunkCounts + (b * NCAM + c) * 256;
        int4 v4 = ((const int4*)p)[lane];            // 4 consecutive counts
        int s = v4.x + v4.y + v4.z + v4.w;
        int incl = s;
        #pragma unroll
        for (int off = 1; off < 64; off <<= 1) {
            int n = __shfl_up(incl, off, 64);
            if (lane >= off) incl += n;
        }
        if (lane == (chunk >> 2)) {
            int base = incl - s;
            int k = chunk & 3;
            if (k > 0) base += v4.x;
            if (k > 1) base += v4.y;
            if (k > 2) base += v4.z;
            sBase[c] = base;
        }
        if (lane == 63) sTotal[c] = incl;
    }

    int q  = chunk * 256 + t;       // this block: qy == chunk, qx == t
    int qx = t, qy = chunk;
    float x, y; bev_xy(qx, qy, x, y);

    int rnk[NCAM];                  // per-thread rank (or -1) per camera

    // phase 1: per camera — project, scan, packed scatter, tail fill
    for (int c = 0; c < NCAM; ++c) {
        float m[12]; load_mat(ego2img, b * NCAM + c, m);
        float uv[8];
        bool vis = false;
        #pragma unroll
        for (int d = 0; d < 4; ++d) {
            float u, v;
            bool vi = proj_point(m, x, y, zval(d), u, v);
            uv[2*d]   = clip21(u);
            uv[2*d+1] = clip21(v);
            vis |= vi;
        }
        int cnt = vis ? 1 : 0;
        int incl = cnt;
        #pragma unroll
        for (int off = 1; off < 64; off <<= 1) {
            int n = __shfl_up(incl, off, 64);
            if (lane >= off) incl += n;
        }
        if (lane == 63) waveIncl[c][wid] = incl;
        __syncthreads();
        int base = sBase[c];
        #pragma unroll
        for (int w = 0; w < 3; ++w) if (w < wid) base += waveIncl[c][w];
        int r = base + incl - cnt;   // packed rank of this q if visible

        float2* qgrid = (float2*)(out + OFF_QGRID)  + (size_t)(b * NCAM + c) * MAXLEN_;
        float4* refp  = (float4*)(out + OFF_REFPTS) + (size_t)(b * NCAM + c) * MAXLEN_ * 2;

        if (vis) {
            float2 g;
            g.x = ((float)qx / 255.0f) * 2.0f - 1.0f;
            g.y = ((float)qy / 255.0f) * 2.0f - 1.0f;
            qgrid[r] = g;
            refp[2*r]   = make_float4(uv[0], uv[1], uv[2], uv[3]);
            refp[2*r+1] = make_float4(uv[4], uv[5], uv[6], uv[7]);
            rnk[c] = r;
        } else {
            rnk[c] = -1;
        }
        // tail fill: slots >= row total get defaults (covers all slots once)
        if (q >= sTotal[c]) {
            qgrid[q] = make_float2(-1.5f, -1.5f);
            float4 z4 = make_float4(0.f, 0.f, 0.f, 0.f);
            refp[2*q]   = z4;
            refp[2*q+1] = z4;
        }
    }

    // phase 2: stage restore row in LDS (column t owned by thread t; the
    // per-lane LDS writes alias banks only 2-way, which is free)
    int over = 0;
    #pragma unroll
    for (int c = 0; c < NCAM; ++c) {
        int r = rnk[c];
        if (r >= 0) {
            float gx = ((float)(r & 255) / 255.0f) * 2.0f - 1.0f;
            float gy = ((float)(c * 256 + (r >> 8)) / 1535.0f) * 2.0f - 1.0f;
            srow[over][t] = make_float2(gx, gy);
            ++over;
        }
    }
    for (int o = over; o < NCAM; ++o)
        srow[o][t] = make_float2(-1.5f, -1.5f);
    out[OFF_COUNTS + b * NQ + q] = 1.0f / fmaxf((float)over, 1.0f);
    __syncthreads();

    // phase 3: write 6 fully-coalesced 2KB plane rows (complete cache lines)
    float2* rest = (float2*)(out + OFF_RESTORE) + (size_t)b * NCAM * NQ;
    #pragma unroll
    for (int o = 0; o < NCAM; ++o)
        rest[(o * 256 + qy) * 256 + t] = srow[o][t];
}

extern "C" void kernel_launch(void* const* d_in, const int* in_sizes, int n_in,
                              void* d_out, int out_size, void* d_ws, size_t ws_size,
                              hipStream_t stream)
{
    const float* ego2img = (const float*)d_in[0];
    float* out = (float*)d_out;
    int* chunkCounts = (int*)d_ws;   // 24*256 ints = 24.6 KB

    k_count<<<dim3(64, NROWS), 256, 0, stream>>>(ego2img, chunkCounts);
    k_fused<<<dim3(256, NB),   256, 0, stream>>>(ego2img, chunkCounts, out);
}

// Round 5
// 91.779 us; speedup vs baseline: 1.8851x; 1.0853x over previous
//
#include <hip/hip_runtime.h>

// ---- problem constants ----
#define NCAM      6
#define NB        4
#define NROWS     24          // NB*NCAM
#define NQ        65536       // 256*256
#define MAXLEN_   65536

// flat f32 offsets into d_out (return order)
#define OFF_QGRID   0
#define OFF_RESTORE 3145728    // 24*65536*2
#define OFF_REFPTS  6291456    // + 4*6*256*256*2
#define OFF_COUNTS  18874368   // + 24*65536*4*2

// z values of the 4 pillar points, f32-linspace path
__device__ __forceinline__ float zval(int d) {
    const float z[4] = { -4.5f, -2.16666674613952637f,
                          0.166666507720947266f, 2.5f };
    return z[d];
}

__device__ __forceinline__ float clip21(float x) {
    return fminf(fmaxf(x, -2.1f), 2.1f);
}

// Project one 3D point. Visibility via multiply-form (no divides):
//   u>0 <=> c0>0 (division is sign-exact), u<1 <=> c0 < 928*zcl, etc.
// Stored u,v via v_rcp (<=3 ulp; output threshold is 4.2e-2).
// IDENTICAL inline used by both kernels so vis decisions match bit-for-bit.
__device__ __forceinline__ bool proj_point(const float m[12], float x, float y, float z,
                                           float& u, float& v) {
    float c0 = ((m[0]*x + m[1]*y) + m[2]*z) + m[3];
    float c1 = ((m[4]*x + m[5]*y) + m[6]*z) + m[7];
    float c2 = ((m[8]*x + m[9]*y) + m[10]*z) + m[11];
    float zcl = fmaxf(c2, 1e-5f);
    float inv = __builtin_amdgcn_rcpf(zcl);
    u = (c0 * inv) * (1.0f / 928.0f);   // IMW
    v = (c1 * inv) * (1.0f / 512.0f);   // IMH
    return (c2 > 1e-5f) & (c1 > 0.0f) & (c1 < 512.0f * zcl)
         & (c0 > 0.0f) & (c0 < 928.0f * zcl);
}

__device__ __forceinline__ void load_mat(const float* __restrict__ ego2img, int row, float m[12]) {
    const float* M = ego2img + row * 16;
    #pragma unroll
    for (int i = 0; i < 12; ++i) m[i] = M[i];
}

__device__ __forceinline__ void bev_xy(int qx, int qy, float& x, float& y) {
    x = ((float)qx + 0.5f) * (1.0f/256.0f) * 102.4f - 51.2f;
    y = ((float)qy + 0.5f) * (1.0f/256.0f) * 102.4f - 51.2f;
}

// ---------- kernel 1: per-256q-subchunk visible-pillar counts ----------
// grid (64, 24), 256 threads. Each wave owns 256 consecutive q -> one count.
// proj_point's u,v are dead here -> rcp DCE'd; pure FMA+CMP kernel.
__global__ void __launch_bounds__(256)
k_count(const float* __restrict__ ego2img, int* __restrict__ chunkCounts)
{
    int chunk = blockIdx.x, row = blockIdx.y;
    float m[12]; load_mat(ego2img, row, m);
    int t = threadIdx.x;
    int q0 = chunk * 1024 + t * 4;
    int cnt = 0;
    #pragma unroll
    for (int i = 0; i < 4; ++i) {
        int q = q0 + i;
        float x, y; bev_xy(q & 255, q >> 8, x, y);
        bool va = false;
        #pragma unroll
        for (int d = 0; d < 4; ++d) {
            float u, v;
            va |= proj_point(m, x, y, zval(d), u, v);
        }
        cnt += va ? 1 : 0;
    }
    #pragma unroll
    for (int off = 32; off > 0; off >>= 1) cnt += __shfl_down(cnt, off, 64);
    if ((t & 63) == 0)
        chunkCounts[row * 256 + chunk * 4 + (t >> 6)] = cnt;
}

// ---------- kernel 2: fused pack + restore + counts ----------
// grid (256, NB), 256 threads. Block = one BEV row (qy = blockIdx.x) of one
// batch, all 6 cameras. refp packed data staged in padded LDS, then written
// as lane-consecutive float4 runs (full 64B lines); tail fills are flat
// coalesced float4/float2 runs.
__global__ void __launch_bounds__(256)
k_fused(const float* __restrict__ ego2img, const int* __restrict__ chunkCounts,
        float* __restrict__ out)
{
    int chunk = blockIdx.x, b = blockIdx.y;
    int t = threadIdx.x;
    int lane = t & 63, wid = t >> 6;

    __shared__ int sBase[NCAM], sTotal[NCAM];
    __shared__ int waveIncl[NCAM][4];
    __shared__ __align__(16) float spack[256 * 12];  // 12 dwords/slot (pad for banks+align)
    __shared__ float2 srow[NCAM][256];               // staged restore row

    // phase 0: per-camera exclusive prefix over the row's 256 subchunk counts
    for (int c = wid; c < NCAM; c += 4) {
        const int* p = chunkCounts + (b * NCAM + c) * 256;
        int4 v4 = ((const int4*)p)[lane];            // 4 consecutive counts
        int s = v4.x + v4.y + v4.z + v4.w;
        int incl = s;
        #pragma unroll
        for (int off = 1; off < 64; off <<= 1) {
            int n = __shfl_up(incl, off, 64);
            if (lane >= off) incl += n;
        }
        if (lane == (chunk >> 2)) {
            int base = incl - s;
            int k = chunk & 3;
            if (k > 0) base += v4.x;
            if (k > 1) base += v4.y;
            if (k > 2) base += v4.z;
            sBase[c] = base;
        }
        if (lane == 63) sTotal[c] = incl;
    }

    int q  = chunk * 256 + t;       // this block: qy == chunk, qx == t
    int qx = t, qy = chunk;
    float x, y; bev_xy(qx, qy, x, y);

    int rnk[NCAM];                  // per-thread rank (or -1) per camera

    // phase 1: per camera — project, scan, LDS-staged packed scatter, tail fill
    for (int c = 0; c < NCAM; ++c) {
        float m[12]; load_mat(ego2img, b * NCAM + c, m);
        float uv[8];
        bool vis = false;
        #pragma unroll
        for (int d = 0; d < 4; ++d) {
            float u, v;
            bool vi = proj_point(m, x, y, zval(d), u, v);
            uv[2*d]   = clip21(u);
            uv[2*d+1] = clip21(v);
            vis |= vi;
        }
        int cnt = vis ? 1 : 0;
        int incl = cnt;
        #pragma unroll
        for (int off = 1; off < 64; off <<= 1) {
            int n = __shfl_up(incl, off, 64);
            if (lane >= off) incl += n;
        }
        if (lane == 63) waveIncl[c][wid] = incl;
        __syncthreads();                       // barrier A (also protects spack reuse)
        int base = sBase[c];
        #pragma unroll
        for (int w = 0; w < 3; ++w) if (w < wid) base += waveIncl[c][w];
        int r = base + incl - cnt;   // packed rank of this q if visible
        int blockBase = sBase[c];
        int blockCnt  = waveIncl[c][0] + waveIncl[c][1] + waveIncl[c][2] + waveIncl[c][3];

        float2* qgrid  = (float2*)(out + OFF_QGRID)  + (size_t)(b * NCAM + c) * MAXLEN_;
        float4* refpF4 = (float4*)(out + OFF_REFPTS) + (size_t)(b * NCAM + c) * (MAXLEN_ * 2);

        if (vis) {
            float2 g;
            g.x = ((float)qx / 255.0f) * 2.0f - 1.0f;
            g.y = ((float)qy / 255.0f) * 2.0f - 1.0f;
            qgrid[r] = g;                       // 8B/slot, consecutive ranks -> full lines
            int s = r - blockBase;              // slot inside this block's packed run
            *(float4*)&spack[12*s]     = make_float4(uv[0], uv[1], uv[2], uv[3]);
            *(float4*)&spack[12*s + 4] = make_float4(uv[4], uv[5], uv[6], uv[7]);
            rnk[c] = r;
        } else {
            rnk[c] = -1;
        }
        __syncthreads();                       // barrier B: spack ready

        // copy-out: block's packed refp run as lane-consecutive float4s
        for (int i = t; i < 2 * blockCnt; i += 256) {
            float4 f = *(float4*)&spack[12*(i >> 1) + 4*(i & 1)];
            refpF4[2*blockBase + i] = f;
        }

        // tail fill (flat, coalesced): block owns slots [256*chunk, 256*chunk+256)
        int s0 = max(sTotal[c], chunk << 8);
        int n  = ((chunk + 1) << 8) - s0;
        if (n > 0) {
            for (int i = t; i < n; i += 256)
                qgrid[s0 + i] = make_float2(-1.5f, -1.5f);
            float4 z4 = make_float4(0.f, 0.f, 0.f, 0.f);
            for (int i = t; i < 2 * n; i += 256)
                refpF4[2*s0 + i] = z4;
        }
    }

    // phase 2: stage restore row in LDS (column t owned by thread t)
    int over = 0;
    #pragma unroll
    for (int c = 0; c < NCAM; ++c) {
        int r = rnk[c];
        if (r >= 0) {
            float gx = ((float)(r & 255) / 255.0f) * 2.0f - 1.0f;
            float gy = ((float)(c * 256 + (r >> 8)) / 1535.0f) * 2.0f - 1.0f;
            srow[over][t] = make_float2(gx, gy);
            ++over;
        }
    }
    for (int o = over; o < NCAM; ++o)
        srow[o][t] = make_float2(-1.5f, -1.5f);
    out[OFF_COUNTS + b * NQ + q] = 1.0f / fmaxf((float)over, 1.0f);
    __syncthreads();

    // phase 3: write 6 fully-coalesced 2KB plane rows (complete cache lines)
    float2* rest = (float2*)(out + OFF_RESTORE) + (size_t)b * NCAM * NQ;
    #pragma unroll
    for (int o = 0; o < NCAM; ++o)
        rest[(o * 256 + qy) * 256 + t] = srow[o][t];
}

extern "C" void kernel_launch(void* const* d_in, const int* in_sizes, int n_in,
                              void* d_out, int out_size, void* d_ws, size_t ws_size,
                              hipStream_t stream)
{
    const float* ego2img = (const float*)d_in[0];
    float* out = (float*)d_out;
    int* chunkCounts = (int*)d_ws;   // 24*256 ints = 24.6 KB

    k_count<<<dim3(64, NROWS), 256, 0, stream>>>(ego2img, chunkCounts);
    k_fused<<<dim3(256, NB),   256, 0, stream>>>(ego2img, chunkCounts, out);
}